// Round 1
// baseline (222.221 us; speedup 1.0000x reference)
//
#include <hip/hip_runtime.h>

// Kernel 1: out[t,b,:] = p_gen[t,b] * vocab[t,b,:V], zeros in the OOV pad.
// Vectorized float4 streaming. blockIdx.x = row (t*B+b), blockIdx.y = chunk.
__global__ void pg_main_kernel(const float* __restrict__ p_gen,
                               const float* __restrict__ vocab,
                               float* __restrict__ out,
                               int V4, int E4) {
    const int row       = blockIdx.x;
    const int nchunk    = gridDim.y;
    const int chunk     = blockIdx.y;
    const int chunkSize = (E4 + nchunk - 1) / nchunk;
    const int lo        = chunk * chunkSize;
    const int hi        = min(E4, lo + chunkSize);

    const float pg = p_gen[row];  // p_gen is (T,B,1) -> flat row index

    const float4* __restrict__ v4 = (const float4*)vocab + (size_t)row * V4;
    float4* __restrict__       o4 = (float4*)out + (size_t)row * E4;

    for (int i = lo + (int)threadIdx.x; i < hi; i += blockDim.x) {
        float4 r;
        if (i < V4) {
            float4 a = v4[i];
            r.x = pg * a.x; r.y = pg * a.y; r.z = pg * a.z; r.w = pg * a.w;
        } else {
            r.x = 0.f; r.y = 0.f; r.z = 0.f; r.w = 0.f;
        }
        o4[i] = r;
    }
}

// Kernel 2: scatter-add (1-p_gen[t,b]) * attn[t,b,s] into out[t,b, ids[b,s]].
// One row (t,b) per block; ids may repeat within a row -> atomicAdd.
__global__ void pg_scatter_kernel(const float* __restrict__ p_gen,
                                  const float* __restrict__ attn,
                                  const int* __restrict__ ids,
                                  float* __restrict__ out,
                                  int B, int S, int E) {
    const int row = blockIdx.x;      // t*B + b
    const int b   = row % B;         // uniform per block (scalar)
    const float w = 1.0f - p_gen[row];

    const float* __restrict__ arow = attn + (size_t)row * S;
    const int* __restrict__   irow = ids  + (size_t)b   * S;
    float* __restrict__       orow = out  + (size_t)row * E;

    for (int s = (int)threadIdx.x; s < S; s += blockDim.x) {
        atomicAdd(&orow[irow[s]], w * arow[s]);
    }
}

extern "C" void kernel_launch(void* const* d_in, const int* in_sizes, int n_in,
                              void* d_out, int out_size, void* d_ws, size_t ws_size,
                              hipStream_t stream) {
    const float* p_gen = (const float*)d_in[0];   // (T,B,1)
    const float* vocab = (const float*)d_in[1];   // (T,B,V)
    const float* attn  = (const float*)d_in[2];   // (T,B,S)
    const int*   ids   = (const int*)d_in[3];     // (B,S)
    // d_in[4] = oov_count (unused by reference), d_in[5] = max_oov (derived from sizes)
    float* out = (float*)d_out;

    const int TB = in_sizes[0];           // T*B  (p_gen flat size)
    const int B  = in_sizes[4];           // oov_count is (B,)
    const int S  = in_sizes[3] / B;       // enc_extended_ids is (B,S)
    const int V  = in_sizes[1] / TB;      // vocab_dist is (T,B,V)
    const int E  = out_size / TB;         // V + max_oov

    const int V4 = V / 4;                 // 50000 % 4 == 0
    const int E4 = E / 4;                 // 50064 % 4 == 0

    // Streaming pass: 2048 blocks (TB=512 rows x 4 chunks), 256 threads.
    dim3 grid1(TB, 4, 1);
    pg_main_kernel<<<grid1, 256, 0, stream>>>(p_gen, vocab, out, V4, E4);

    // Scatter pass: one block per row, tiny.
    pg_scatter_kernel<<<TB, 256, 0, stream>>>(p_gen, attn, ids, out, B, S, E);
}

// Round 3
// 211.409 us; speedup vs baseline: 1.0511x; 1.0511x over previous
//
#include <hip/hip_runtime.h>

typedef float vf4 __attribute__((ext_vector_type(4)));  // clang vector: OK for nontemporal builtins

// Fused kernel: one block per (t,b) row.
//  Phase 1: out[row, :V] = p_gen[row] * vocab[row, :V]; out[row, V:E] = 0  (float4)
//  Phase 2: (after __syncthreads) scatter-add (1-p_gen[row])*attn[row,s]
//           into out[row, ids[b,s]] with atomics (ids repeat within a row).
// All writes/atomics are row-local -> no inter-kernel dependency, L2-hot RMW.
__global__ __launch_bounds__(1024, 2) void pg_fused_kernel(
        const float* __restrict__ p_gen,
        const float* __restrict__ vocab,
        const float* __restrict__ attn,
        const int* __restrict__ ids,
        float* __restrict__ out,
        int B, int S, int V4, int E4, int E) {
    const int row = blockIdx.x;          // t*B + b
    const int b   = row - (row / B) * B; // row % B, uniform per block
    const float pg = p_gen[row];

    const vf4* __restrict__ v4 = (const vf4*)vocab + (size_t)row * V4;
    vf4* __restrict__       o4 = (vf4*)out + (size_t)row * E4;

    // Phase 1: streaming scale + zero pad. vocab is read-once -> nontemporal.
    for (int i = (int)threadIdx.x; i < E4; i += blockDim.x) {
        vf4 r = (vf4)(0.f);
        if (i < V4) {
            vf4 a = __builtin_nontemporal_load(&v4[i]);
            r = pg * a;
        }
        o4[i] = r;
    }

    __syncthreads();

    // Phase 2: scatter-add into this row (atomics: duplicate ids possible).
    const float w = 1.0f - pg;
    const float* __restrict__ arow = attn + (size_t)row * S;
    const int* __restrict__   irow = ids  + (size_t)b   * S;
    float* __restrict__       orow = out  + (size_t)row * E;
    for (int s = (int)threadIdx.x; s < S; s += blockDim.x) {
        atomicAdd(&orow[irow[s]], w * arow[s]);
    }
}

extern "C" void kernel_launch(void* const* d_in, const int* in_sizes, int n_in,
                              void* d_out, int out_size, void* d_ws, size_t ws_size,
                              hipStream_t stream) {
    const float* p_gen = (const float*)d_in[0];   // (T,B,1)
    const float* vocab = (const float*)d_in[1];   // (T,B,V)
    const float* attn  = (const float*)d_in[2];   // (T,B,S)
    const int*   ids   = (const int*)d_in[3];     // (B,S)
    // d_in[4] = oov_count (unused by reference)
    float* out = (float*)d_out;

    const int TB = in_sizes[0];           // T*B
    const int B  = in_sizes[4];           // oov_count is (B,)
    const int S  = in_sizes[3] / B;       // enc_extended_ids is (B,S)
    const int V  = in_sizes[1] / TB;      // vocab_dist is (T,B,V)
    const int E  = out_size / TB;         // V + max_oov

    const int V4 = V / 4;                 // 50000 % 4 == 0
    const int E4 = E / 4;                 // 50064 % 4 == 0

    pg_fused_kernel<<<TB, 1024, 0, stream>>>(p_gen, vocab, attn, ids, out,
                                             B, S, V4, E4, E);
}